// Round 4
// baseline (401.625 us; speedup 1.0000x reference)
//
#include <hip/hip_runtime.h>

#define PTAB_STRIDE 64
typedef float f2 __attribute__((ext_vector_type(2)));

__device__ __forceinline__ f2 fma2(f2 a, f2 b, f2 c) {
    return __builtin_elementwise_fma(a, b, c);
}

// ---------------------------------------------------------------------------
// Phase 1: ptab[v][h] = dot(emb[v,:], W_ih[h,:]) + b_ih[h] + b_hh[h]
// Lane -> vocab row. Each thread streams its own emb row (float4, double-
// buffered), holds acc[50] in VGPRs, and reads W_ih via wave-uniform scalar
// loads (s_load_dwordx16 per h per 16-k block). No LDS, no barriers.
// ---------------------------------------------------------------------------
__global__ __launch_bounds__(256) void ptab_kernel(
    const float* __restrict__ emb, const float* __restrict__ Wih,
    const float* __restrict__ bih, const float* __restrict__ bhh,
    float* __restrict__ ptab)
{
    int v = blockIdx.x * 256 + threadIdx.x;
    const bool valid = v < 50000;
    if (!valid) v = 49999;
    const float4* row4 = (const float4*)(emb + (size_t)v * 300);

    float acc[50];
    #pragma unroll
    for (int h = 0; h < 50; ++h) acc[h] = 0.f;

    // 75 float4 chunks per row: 18 blocks of 16 floats + 12-float tail
    float4 c0 = row4[0], c1 = row4[1], c2 = row4[2], c3 = row4[3];

    #pragma unroll 1
    for (int kb = 0; kb < 18; ++kb) {
        const int nb = kb * 4 + 4;
        float4 n0 = row4[nb];
        float4 n1 = row4[nb + 1];
        float4 n2 = row4[nb + 2];
        float4 n3 = (kb < 17) ? row4[nb + 3] : row4[74];

        const float* wb = Wih + kb * 16;
        #pragma unroll
        for (int hp = 0; hp < 25; ++hp) {
            const float* wa = wb + (2 * hp) * 300;      // uniform -> s_load
            const float* wc = wb + (2 * hp + 1) * 300;
            float a = acc[2 * hp], c = acc[2 * hp + 1];
            a = fmaf(c0.x, wa[0],  a);  c = fmaf(c0.x, wc[0],  c);
            a = fmaf(c0.y, wa[1],  a);  c = fmaf(c0.y, wc[1],  c);
            a = fmaf(c0.z, wa[2],  a);  c = fmaf(c0.z, wc[2],  c);
            a = fmaf(c0.w, wa[3],  a);  c = fmaf(c0.w, wc[3],  c);
            a = fmaf(c1.x, wa[4],  a);  c = fmaf(c1.x, wc[4],  c);
            a = fmaf(c1.y, wa[5],  a);  c = fmaf(c1.y, wc[5],  c);
            a = fmaf(c1.z, wa[6],  a);  c = fmaf(c1.z, wc[6],  c);
            a = fmaf(c1.w, wa[7],  a);  c = fmaf(c1.w, wc[7],  c);
            a = fmaf(c2.x, wa[8],  a);  c = fmaf(c2.x, wc[8],  c);
            a = fmaf(c2.y, wa[9],  a);  c = fmaf(c2.y, wc[9],  c);
            a = fmaf(c2.z, wa[10], a);  c = fmaf(c2.z, wc[10], c);
            a = fmaf(c2.w, wa[11], a);  c = fmaf(c2.w, wc[11], c);
            a = fmaf(c3.x, wa[12], a);  c = fmaf(c3.x, wc[12], c);
            a = fmaf(c3.y, wa[13], a);  c = fmaf(c3.y, wc[13], c);
            a = fmaf(c3.z, wa[14], a);  c = fmaf(c3.z, wc[14], c);
            a = fmaf(c3.w, wa[15], a);  c = fmaf(c3.w, wc[15], c);
            acc[2 * hp] = a; acc[2 * hp + 1] = c;
        }
        c0 = n0; c1 = n1; c2 = n2; c3 = n3;
    }
    // tail: k = 288..299 in c0,c1,c2
    {
        const float* wb = Wih + 288;
        #pragma unroll
        for (int hp = 0; hp < 25; ++hp) {
            const float* wa = wb + (2 * hp) * 300;
            const float* wc = wb + (2 * hp + 1) * 300;
            float a = acc[2 * hp], c = acc[2 * hp + 1];
            a = fmaf(c0.x, wa[0],  a);  c = fmaf(c0.x, wc[0],  c);
            a = fmaf(c0.y, wa[1],  a);  c = fmaf(c0.y, wc[1],  c);
            a = fmaf(c0.z, wa[2],  a);  c = fmaf(c0.z, wc[2],  c);
            a = fmaf(c0.w, wa[3],  a);  c = fmaf(c0.w, wc[3],  c);
            a = fmaf(c1.x, wa[4],  a);  c = fmaf(c1.x, wc[4],  c);
            a = fmaf(c1.y, wa[5],  a);  c = fmaf(c1.y, wc[5],  c);
            a = fmaf(c1.z, wa[6],  a);  c = fmaf(c1.z, wc[6],  c);
            a = fmaf(c1.w, wa[7],  a);  c = fmaf(c1.w, wc[7],  c);
            a = fmaf(c2.x, wa[8],  a);  c = fmaf(c2.x, wc[8],  c);
            a = fmaf(c2.y, wa[9],  a);  c = fmaf(c2.y, wc[9],  c);
            a = fmaf(c2.z, wa[10], a);  c = fmaf(c2.z, wc[10], c);
            a = fmaf(c2.w, wa[11], a);  c = fmaf(c2.w, wc[11], c);
            acc[2 * hp] = a; acc[2 * hp + 1] = c;
        }
    }

    if (valid) {
        float* prow = ptab + (size_t)v * PTAB_STRIDE;
        #pragma unroll
        for (int hp = 0; hp < 25; ++hp) {
            float2 o;
            o.x = acc[2 * hp]     + bih[2 * hp]     + bhh[2 * hp];
            o.y = acc[2 * hp + 1] + bih[2 * hp + 1] + bhh[2 * hp + 1];
            *(float2*)(prow + 2 * hp) = o;
        }
        #pragma unroll
        for (int j = 0; j < 7; ++j)              // zero cols 50..63
            *(float2*)(prow + 50 + 2 * j) = make_float2(0.f, 0.f);
    }
}

// ---------------------------------------------------------------------------
// Phase 2: recurrence + head. One wave per batch element, 1 wave/SIMD spread
// over 256 CUs. h broadcast: 1 ds_write_b32 + 12 ds_read_b128 + 1 ds_read_b64
// (uniform address = LDS broadcast; same-wave DS ops are in-order, no
// barrier). Dot product: 25 v_pk_fma_f32. b_ih+b_hh pre-folded into ptab.
// ---------------------------------------------------------------------------
__global__ __launch_bounds__(64) void rnn_kernel(
    const int* __restrict__ tokens, const float* __restrict__ ptab,
    const float* __restrict__ Whh,
    const float* __restrict__ Wfc, const float* __restrict__ bfc,
    float* __restrict__ out)
{
    __shared__ int   stok[544];
    __shared__ float hbuf[64];
    const int lane = threadIdx.x;
    const int b    = blockIdx.x;
    const int hc   = lane < 50 ? lane : 49;

    #pragma unroll
    for (int k = 0; k < 8; ++k)
        stok[lane + 64 * k] = tokens[b * 512 + lane + 64 * k];
    if (lane < 32) stok[512 + lane] = 0;     // pad: token 0 -> valid row
    __syncthreads();

    f2 whh2[25];
    #pragma unroll
    for (int j = 0; j < 25; ++j) {
        float2 w2 = *(const float2*)(Whh + hc * 50 + 2 * j);
        whh2[j].x = w2.x; whh2[j].y = w2.y;
    }

    float h = 0.f;

#define GATHER(T) ptab[(size_t)(T) * PTAB_STRIDE + lane]

    float x0 = GATHER(stok[0]), x1 = GATHER(stok[1]);
    float x2 = GATHER(stok[2]), x3 = GATHER(stok[3]);
    float x4 = GATHER(stok[4]), x5 = GATHER(stok[5]);
    float x6 = GATHER(stok[6]), x7 = GATHER(stok[7]);
    int k0 = stok[8],  k1 = stok[9],  k2 = stok[10], k3 = stok[11];
    int k4 = stok[12], k5 = stok[13], k6 = stok[14], k7 = stok[15];

#define RNN_STEP(XV)                                                        \
    {                                                                       \
        hbuf[lane] = h;                    /* ds_write_b32, in-order */     \
        const float4* hb4 = (const float4*)hbuf;                            \
        float4 h0 = hb4[0], h1 = hb4[1], h2 = hb4[2];                       \
        float4 h3 = hb4[3], h4 = hb4[4], h5 = hb4[5];                       \
        float4 h6 = hb4[6], h7 = hb4[7], h8 = hb4[8];                       \
        float4 h9 = hb4[9], h10 = hb4[10], h11 = hb4[11];                   \
        float2 h12 = *(const float2*)&hbuf[48];                             \
        f2 a0 = {0.f, 0.f}, a1 = {0.f, 0.f};                                \
        a0 = fma2((f2){h0.x,  h0.y},  whh2[0],  a0);                        \
        a1 = fma2((f2){h0.z,  h0.w},  whh2[1],  a1);                        \
        a0 = fma2((f2){h1.x,  h1.y},  whh2[2],  a0);                        \
        a1 = fma2((f2){h1.z,  h1.w},  whh2[3],  a1);                        \
        a0 = fma2((f2){h2.x,  h2.y},  whh2[4],  a0);                        \
        a1 = fma2((f2){h2.z,  h2.w},  whh2[5],  a1);                        \
        a0 = fma2((f2){h3.x,  h3.y},  whh2[6],  a0);                        \
        a1 = fma2((f2){h3.z,  h3.w},  whh2[7],  a1);                        \
        a0 = fma2((f2){h4.x,  h4.y},  whh2[8],  a0);                        \
        a1 = fma2((f2){h4.z,  h4.w},  whh2[9],  a1);                        \
        a0 = fma2((f2){h5.x,  h5.y},  whh2[10], a0);                        \
        a1 = fma2((f2){h5.z,  h5.w},  whh2[11], a1);                        \
        a0 = fma2((f2){h6.x,  h6.y},  whh2[12], a0);                        \
        a1 = fma2((f2){h6.z,  h6.w},  whh2[13], a1);                        \
        a0 = fma2((f2){h7.x,  h7.y},  whh2[14], a0);                        \
        a1 = fma2((f2){h7.z,  h7.w},  whh2[15], a1);                        \
        a0 = fma2((f2){h8.x,  h8.y},  whh2[16], a0);                        \
        a1 = fma2((f2){h8.z,  h8.w},  whh2[17], a1);                        \
        a0 = fma2((f2){h9.x,  h9.y},  whh2[18], a0);                        \
        a1 = fma2((f2){h9.z,  h9.w},  whh2[19], a1);                        \
        a0 = fma2((f2){h10.x, h10.y}, whh2[20], a0);                        \
        a1 = fma2((f2){h10.z, h10.w}, whh2[21], a1);                        \
        a0 = fma2((f2){h11.x, h11.y}, whh2[22], a0);                        \
        a1 = fma2((f2){h11.z, h11.w}, whh2[23], a1);                        \
        a0 = fma2((f2){h12.x, h12.y}, whh2[24], a0);                        \
        f2 sv = a0 + a1;                                                    \
        float a = (XV) + (sv.x + sv.y);                                     \
        a = fminf(9.f, fmaxf(-9.f, a));                                     \
        float e = __expf(2.f * a);                                          \
        h = fmaf(-2.f, __builtin_amdgcn_rcpf(e + 1.f), 1.f);                \
    }

    for (int t = 0; t < 512; t += 8) {
        float n0 = GATHER(k0), n1 = GATHER(k1), n2 = GATHER(k2), n3 = GATHER(k3);
        float n4 = GATHER(k4), n5 = GATHER(k5), n6 = GATHER(k6), n7 = GATHER(k7);
        k0 = stok[t + 16]; k1 = stok[t + 17]; k2 = stok[t + 18]; k3 = stok[t + 19];
        k4 = stok[t + 20]; k5 = stok[t + 21]; k6 = stok[t + 22]; k7 = stok[t + 23];

        RNN_STEP(x0); RNN_STEP(x1); RNN_STEP(x2); RNN_STEP(x3);
        RNN_STEP(x4); RNN_STEP(x5); RNN_STEP(x6); RNN_STEP(x7);

        x0 = n0; x1 = n1; x2 = n2; x3 = n3;
        x4 = n4; x5 = n5; x6 = n6; x7 = n7;
    }
#undef RNN_STEP
#undef GATHER

    // ---- head: out[b][o] = sum_h h[h] * W_fc[o][h] + b_fc[o] ----
    float hv = (lane < 50) ? h : 0.f;
    #pragma unroll
    for (int o = 0; o < 4; ++o) {
        float w = (lane < 50) ? Wfc[o * 50 + lane] : 0.f;
        float p = hv * w;
        #pragma unroll
        for (int s = 32; s > 0; s >>= 1) p += __shfl_xor(p, s, 64);
        if (lane == 0) out[b * 4 + o] = p + bfc[o];
    }
}

extern "C" void kernel_launch(void* const* d_in, const int* in_sizes, int n_in,
                              void* d_out, int out_size, void* d_ws, size_t ws_size,
                              hipStream_t stream)
{
    const int*   tokens = (const int*)d_in[0];
    const float* emb    = (const float*)d_in[1];
    const float* Wih    = (const float*)d_in[2];
    const float* Whh    = (const float*)d_in[3];
    const float* bih    = (const float*)d_in[4];
    const float* bhh    = (const float*)d_in[5];
    const float* Wfc    = (const float*)d_in[6];
    const float* bfc    = (const float*)d_in[7];

    float* ptab = (float*)d_ws;          // 50000 * 64 * 4 B = 12.8 MB
    float* outp = (float*)d_out;

    ptab_kernel<<<196, 256, 0, stream>>>(emb, Wih, bih, bhh, ptab);
    rnn_kernel<<<256, 64, 0, stream>>>(tokens, ptab, Whh, Wfc, bfc, outp);
}